// Round 4
// baseline (709.126 us; speedup 1.0000x reference)
//
#include <hip/hip_runtime.h>

// Problem constants (fixed by the reference module).
constexpr int B = 4, C = 256, H = 256, W = 512;
constexpr int MAXLOAD = 100, FS = 14;
constexpr int NROI = B * MAXLOAD;            // 400
constexpr int HB = B * H;                    // 1024 (flattened b*h rows)
constexpr int FS2 = FS * FS;                 // 196
constexpr int MAIN = NROI * C * FS2;         // 20,070,400 elements of out[0]
constexpr int CPT = 4;                       // channels per thread (coords shared)
constexpr int MAIN_BLOCKS = MAIN / CPT / 256; // 19,600 (exact)
constexpr int NXCD = 8;
constexpr int CHUNK = MAIN_BLOCKS / NXCD;    // 2,450 (bijective: 19600 % 8 == 0)
constexpr int NCGRP = C / CPT;               // 64 channel groups

__global__ __launch_bounds__(256) void pooler_kernel(
    const float* __restrict__ feats,   // (B,C,H,W) fp32
    const float* __restrict__ rois,    // (B*MAXLOAD, 4) fp32: x0,y0,x1,y1
    float* __restrict__ out)           // (NROI,C,FS,FS) fp32 ++ val_bind(NROI)
{
    int bid = blockIdx.x;

    if (bid >= MAIN_BLOCKS) {
        // val_bind tail: repeat(arange(B), MAXLOAD), written as float
        int t = (bid - MAIN_BLOCKS) * 256 + threadIdx.x;
        if (t < NROI)
            __builtin_nontemporal_store((float)(t / MAXLOAD), &out[MAIN + t]);
        return;
    }

    // XCD-chunk swizzle + channel-group-major enumeration (R1 locality win
    // preserved): each XCD owns a contiguous 1/8 of (g,n) space.
    int wg = (bid % NXCD) * CHUNK + bid / NXCD;
    int e  = wg * 256 + threadIdx.x;

    // e = (g*NROI + n)*FS2 + pos ; thread serves channels c0..c0+3 of (n,pos)
    int pos = e % FS2;
    int t   = e / FS2;
    int n   = t % NROI;
    int g   = t / NROI;          // 0..63
    int c0  = g * CPT;
    int fx  = pos % FS;
    int fy  = pos / FS;
    int vb  = n / MAXLOAD;       // batch of this roi

    float4 roi = reinterpret_cast<const float4*>(rois)[n];
    float scalex = roi.z - roi.x;
    float scaley = roi.w - roi.y;
    float biasx  = roi.x;
    float biasy  = roi.y + (float)vb * 1024.0f;  // image_height = 1024

    // grid coords (dscale = 4); algebraic simplification of the reference's
    // normalize->denormalize round trip (verified: absmax 0.0156, passing).
    float gridx = ((float)fx * (1.0f / 13.0f) * scalex + biasx) * 0.25f;
    float gridy = ((float)fy * (1.0f / 13.0f) * scaley + biasy) * 0.25f;
    float px = gridx * (512.0f / 511.0f) - 0.5f;
    float py = gridy * (1024.0f / 1023.0f) - 0.5f;
    px = fminf(fmaxf(px, 0.0f), (float)(W - 1));
    py = fminf(fmaxf(py, 0.0f), (float)(HB - 1));

    float x0f = floorf(px), y0f = floorf(py);
    float wx = px - x0f, wy = py - y0f;
    int x0 = (int)x0f, y0 = (int)y0f;
    int y1 = min(y0 + 1, HB - 1);

    // feats viewed as (C, HB, W): flat = ((y>>8)*C*H + (y&255))*W + c*H*W + x
    // Coordinates are channel-invariant: compute row offsets once, step c.
    int cb  = c0 * (H * W);
    int ro0 = ((y0 >> 8) * (C * H) + (y0 & (H - 1))) * W + cb;
    int ro1 = ((y1 >> 8) * (C * H) + (y1 & (H - 1))) * W + cb;

    // (f00,f01) share a cache line -> one dwordx2 per row (R3 win). xb clamp
    // keeps the pair in-row; x1 = min(x0+1, W-1) is always the .y element.
    int xb = min(x0, W - 2);
    bool hi = (x0 != xb);        // true only when x0 == W-1

    int out_base = (n * C + c0) * FS2 + pos;

#pragma unroll
    for (int j = 0; j < CPT; ++j) {
        float2 v0 = *reinterpret_cast<const float2*>(&feats[ro0 + j * (H * W) + xb]);
        float2 v1 = *reinterpret_cast<const float2*>(&feats[ro1 + j * (H * W) + xb]);
        float f00 = hi ? v0.y : v0.x;
        float f10 = hi ? v1.y : v1.x;

        float r0 = f00 + wx * (v0.y - f00);
        float r1 = f10 + wx * (v1.y - f10);
        float res = r0 + wy * (r1 - r0);
        __builtin_nontemporal_store(res, &out[out_base + j * FS2]);
    }
}

extern "C" void kernel_launch(void* const* d_in, const int* in_sizes, int n_in,
                              void* d_out, int out_size, void* d_ws, size_t ws_size,
                              hipStream_t stream) {
    const float* feats = (const float*)d_in[0];
    const float* rois  = (const float*)d_in[1];
    float* out = (float*)d_out;

    int tail_blocks = (NROI + 255) / 256;     // 2
    pooler_kernel<<<MAIN_BLOCKS + tail_blocks, 256, 0, stream>>>(feats, rois, out);
}